// Round 9
// baseline (319.880 us; speedup 1.0000x reference)
//
#include <hip/hip_runtime.h>

// BrickVectorEdgeModel on MI355X (gfx950).
// R16: edge -> 1024 threads/block (16 waves, 4 waves/SIMD) at the SAME
// 144-row tile / 1024 blocks / W-per-CU. Post-mortem chain: VALU count
// (R10), W-prefetch depth (R11), tile-size occupancy (R13, confounded by
// 2x W/CU), MFMA shape (R15, killed by 4.5-round grid imbalance; per-row
// neutral) -- all null. The only never-isolated variable: waves/SIMD = 2.
// This doubles TLP with ZERO change to W traffic, tile, or grid: each of
// 16 waves owns 32 out-cols (NT=2), final Wout phase gated to waves 0-7.
// VGPR ~110 under the 128 cap of __launch_bounds__(1024,4); WRITE_SIZE is
// the spill canary. Bank-conflict counter shown to be counted-but-cheap
// (R15: 3.6x drop, no speedup) -- ignored hereafter.
// Nodes/prep: R14-exact (best, 250.7us).
// Tiled W layout (per 512-col weight, elems): off(c,k) =
//   ((c>>4)*16 + (k>>5))*512 + (c&15)*32 + (k&31)

typedef short  short8  __attribute__((ext_vector_type(8)));
typedef short  short4v __attribute__((ext_vector_type(4)));
typedef float  f32x4   __attribute__((ext_vector_type(4)));

#define LDSW 520   // LDS row stride in bf16 elems (520*2B = 1040B, 16B-aligned)

__device__ inline unsigned short f2bf(float x) {
  unsigned u = __float_as_uint(x);
  unsigned r = (u + 0x7FFFu + ((u >> 16) & 1u)) >> 16;  // RNE
  return (unsigned short)r;
}

__device__ __host__ inline int wtile_off(int c, int k) {
  return ((c >> 4) * 16 + (k >> 5)) * 512 + (c & 15) * 32 + (k & 31);
}

template <int MT, int NT>
__device__ inline void zero_acc(f32x4 (&acc)[MT][NT]) {
#pragma unroll
  for (int mt = 0; mt < MT; ++mt)
#pragma unroll
    for (int nt = 0; nt < NT; ++nt) {
      f32x4 z = {0.f, 0.f, 0.f, 0.f};
      acc[mt][nt] = z;
    }
}

// acc[mt][nt] (+)= W-tile x E-tile.  W as MFMA A-operand (m = out-col),
// E as B-operand (n = edge-row).  Lane holds 4 consecutive out-cols
// (kg*4+r) at edge-row (mt*16 + (lane&15)).
// W is in tiled layout: per (col_tile ct, ks) a contiguous 1KB fragment;
// lane's slice at (lane&15)*32 + (lane>>4)*8.  One wF load = coalesced 1KB.
// wF register double-buffered across ks; eF JIT from LDS, rotating 1-deep.
template <int MT, int NT>
__device__ inline void gemm_kloop(const short* E, const short* __restrict__ W,
                                  int lane, int nbase, f32x4 (&acc)[MT][NT]) {
  const int mrow = lane & 15, kg = lane >> 4;
  const short* El = E + mrow * LDSW + kg * 8;
  const short* Wl = W + (nbase >> 4) * 8192 + mrow * 32 + kg * 8;
  short8 wF[2][NT];
#pragma unroll
  for (int nt = 0; nt < NT; ++nt) wF[0][nt] = *(const short8*)(Wl + nt * 8192);
#pragma unroll
  for (int ks = 0; ks < 16; ++ks) {
    const int cur = ks & 1, nxt = cur ^ 1;
    if (ks < 15) {
      const int k1 = (ks + 1) * 512;
#pragma unroll
      for (int nt = 0; nt < NT; ++nt)
        wF[nxt][nt] = *(const short8*)(Wl + nt * 8192 + k1);
    }
    const int k0 = ks * 32;
    short8 e0 = *(const short8*)(El + k0);
#pragma unroll
    for (int mt = 0; mt < MT; ++mt) {
      const short8 ecur = e0;
      if (mt < MT - 1) e0 = *(const short8*)(El + (mt + 1) * 16 * LDSW + k0);
#pragma unroll
      for (int nt = 0; nt < NT; ++nt)
        acc[mt][nt] = __builtin_amdgcn_mfma_f32_16x16x32_bf16(
            wF[cur][nt], ecur, acc[mt][nt], 0, 0, 0);
    }
  }
}

// relu(acc + bias[outcol]) -> bf16 -> LDS, 8B vector writes.
template <int MT, int NT>
__device__ inline void store_relu_lds(short* E, const float* __restrict__ bias,
                                      int lane, int nbase, f32x4 (&acc)[MT][NT]) {
  const int mrow = lane & 15, kg = lane >> 4;
#pragma unroll
  for (int nt = 0; nt < NT; ++nt) {
    const int oc = nbase + nt * 16 + kg * 4;
    const float4 bs = *(const float4*)(bias + oc);
#pragma unroll
    for (int mt = 0; mt < MT; ++mt) {
      short4v s;
      s.x = (short)f2bf(fmaxf(acc[mt][nt][0] + bs.x, 0.f));
      s.y = (short)f2bf(fmaxf(acc[mt][nt][1] + bs.y, 0.f));
      s.z = (short)f2bf(fmaxf(acc[mt][nt][2] + bs.z, 0.f));
      s.w = (short)f2bf(fmaxf(acc[mt][nt][3] + bs.w, 0.f));
      *(short4v*)&E[(mt * 16 + mrow) * LDSW + oc] = s;
    }
  }
}

// ---------------- prep: fp32 -> bf16 + tiled relayout ----------------
__global__ void prep_kernel(const float* __restrict__ Wa, const float* __restrict__ Wb,
                            const float* __restrict__ Wca, const float* __restrict__ Wcb,
                            const float* __restrict__ Wcc, const float* __restrict__ Wout,
                            short* __restrict__ outS) {
  const int tid = blockIdx.x * blockDim.x + threadIdx.x;
  const int stride = gridDim.x * blockDim.x;
  const int M = 262144;
  for (int i = tid; i < 6 * M + 1024; i += stride) {
    float x;
    int dst;
    if (i < M) {                       // WaB tiled
      const int c = i >> 9, k = i & 511;
      x = Wa[i];
      dst = wtile_off(c, k);
    } else if (i < 2 * M) {            // WbB tiled
      const int t = i - M, c = t >> 9, k = t & 511;
      x = Wb[t];
      dst = M + wtile_off(c, k);
    } else if (i < 3 * M) {            // Wuv: u-half, tiled cols 0..511
      const int t = i - 2 * M, c = t >> 9, k = t & 511;
      x = Wca[c * 1024 + k];
      dst = 2 * M + wtile_off(c, k);
    } else if (i < 4 * M) {            // Wuv: v-half, tiled cols 512..1023
      const int t = i - 3 * M, c = t >> 9, k = t & 511;
      x = Wca[c * 1024 + 512 + k];
      dst = 2 * M + wtile_off(512 + c, k);
    } else if (i < 5 * M) {            // WcbB tiled
      const int t = i - 4 * M, c = t >> 9, k = t & 511;
      x = Wcb[t];
      dst = 4 * M + wtile_off(c, k);
    } else if (i < 6 * M) {            // WccB tiled
      const int t = i - 5 * M, c = t >> 9, k = t & 511;
      x = Wcc[t];
      dst = 5 * M + wtile_off(c, k);
    } else {                           // Wout plain row-major
      x = Wout[i - 6 * M];
      dst = i;
    }
    outS[dst] = (short)f2bf(x);
  }
}

// ---------------- node stage: 3 per-layer tiled kernels (16 rows x 64 cols) --
// R14-proven: grids 384/384/768 fill all 256 CUs, ~6 resident blocks/CU.
template <int MODE>
__global__ __launch_bounds__(256, 4) void node_layer(
    const void* __restrict__ Xin, const short* __restrict__ W,
    const float* __restrict__ bias, const float* __restrict__ xy,
    const float* __restrict__ Wxy, const float* __restrict__ bxy,
    void* __restrict__ Yout, float* __restrict__ vout, int colTiles) {
  __shared__ short X[16 * LDSW];
  __shared__ float xyl[32];
  const int tid = threadIdx.x, lane = tid & 63, wave = tid >> 6;
  const int rt = blockIdx.x / colTiles, ct = blockIdx.x % colTiles;
  const int row0 = rt * 16, c0 = ct * 64;

  if (MODE == 1) {
    const float* bv = (const float*)Xin;
    const int hc = (tid & 127) * 4, m0 = tid >> 7;
    for (int m = m0; m < 16; m += 2) {
      const float4 t = *(const float4*)(bv + (row0 + m) * 512 + hc);
      short4v s;
      s.x = (short)f2bf(t.x); s.y = (short)f2bf(t.y);
      s.z = (short)f2bf(t.z); s.w = (short)f2bf(t.w);
      *(short4v*)&X[m * LDSW + hc] = s;
    }
    if (tid < 32) xyl[tid] = xy[row0 * 2 + tid];
  } else {
    const short* xb = (const short*)Xin;
    const int hc = (tid & 63) * 8, m0 = tid >> 6;
    for (int m = m0; m < 16; m += 4)
      *(short8*)&X[m * LDSW + hc] = *(const short8*)(xb + (row0 + m) * 512 + hc);
  }
  __syncthreads();

  const int nbase = c0 + wave * 16;
  f32x4 acc[1][1];
  zero_acc<1, 1>(acc);
  gemm_kloop<1, 1>(X, W, lane, nbase, acc);

  const int mrow = lane & 15, kg = lane >> 4;
  const int oc = nbase + kg * 4;
  if (MODE == 3) {
    float* u = (float*)Yout;
    const int row = row0 + mrow;
    if (oc < 512) *(f32x4*)&u[row * 512 + oc] = acc[0][0];     // block-uniform branch
    else          *(f32x4*)&vout[row * 512 + oc - 512] = acc[0][0];
  } else {
    short* Y = (short*)Yout;
    const float4 bs = *(const float4*)(bias + oc);
    float b2[4] = {0.f, 0.f, 0.f, 0.f}, w0[4], w1[4];
    if (MODE == 1) {
      const float4 t = *(const float4*)(bxy + oc);
      b2[0] = t.x; b2[1] = t.y; b2[2] = t.z; b2[3] = t.w;
#pragma unroll
      for (int r = 0; r < 4; ++r) { w0[r] = Wxy[(oc + r) * 2]; w1[r] = Wxy[(oc + r) * 2 + 1]; }
    }
    const int row = mrow;
    short4v s;
#pragma unroll
    for (int r = 0; r < 4; ++r) {
      float xv = acc[0][0][r] + ((const float*)&bs)[r];
      if (MODE == 1) xv += b2[r] + xyl[row * 2] * w0[r] + xyl[row * 2 + 1] * w1[r];
      ((short*)&s)[r] = (short)f2bf(fmaxf(xv, 0.f));
    }
    *(short4v*)&Y[(row0 + row) * 512 + oc] = s;
  }
}

// ---------------- edge stage: fused E0 -> E1 -> E2 -> out ----------------
// 144-row tiles (3 i x 48 j), 1024 blocks (4 full rounds), LDS 159KB ->
// 1 block/CU -- all R7-identical -- but 1024 THREADS (16 waves, 4/SIMD):
// each wave owns 32 out-cols (NT=2). Doubles latency-hiding TLP at
// IDENTICAL W-traffic. Final Wout phase: waves 0-7 only (red stays 9.2KB).
__global__ __launch_bounds__(1024, 4) void edge_kernel(
    const float* __restrict__ u, const float* __restrict__ v,
    const short* __restrict__ Wcb, const short* __restrict__ Wcc,
    const short* __restrict__ Wout,
    const float* __restrict__ bca, const float* __restrict__ bcb,
    const float* __restrict__ bcc, const float* __restrict__ bout,
    float* __restrict__ out) {
  __shared__ short A[144 * LDSW];      // 149,760 B
  __shared__ float red[144 * 2 * 8];   //   9,216 B
  const int tid = threadIdx.x, lane = tid & 63, wave = tid >> 6;
  const int blk = blockIdx.x;
  const int b = blk >> 8, rem = blk & 255, ip = rem >> 2, jt = rem & 3;
  const float* urow0 = u + (b * 192 + jt * 48) * 512;        // row m: j = jt*48 + m%48
  const float* vrow0 = v + (b * 192 + ip * 3) * 512;         // row m: i = ip*3 + m/48

  {  // Phase 0: E0 = relu(u[j] + v[i] + b_ca) -> bf16 LDS
    const int hc = (tid & 127) * 4, m0 = tid >> 7;   // m0 in 0..7
    const float4 v0 = *(const float4*)(vrow0 + hc);
    const float4 v1 = *(const float4*)(vrow0 + 512 + hc);
    const float4 v2 = *(const float4*)(vrow0 + 1024 + hc);
    const float4 bb = *(const float4*)(bca + hc);
#pragma unroll 2
    for (int m = m0; m < 144; m += 8) {
      const int ii = (m >= 96) ? 2 : (m >= 48 ? 1 : 0);
      const int jj = m - ii * 48;
      const float4 vv = (ii == 0) ? v0 : (ii == 1) ? v1 : v2;
      const float4 uu = *(const float4*)(urow0 + jj * 512 + hc);
      short4v s;
      s.x = (short)f2bf(fmaxf(uu.x + vv.x + bb.x, 0.f));
      s.y = (short)f2bf(fmaxf(uu.y + vv.y + bb.y, 0.f));
      s.z = (short)f2bf(fmaxf(uu.z + vv.z + bb.z, 0.f));
      s.w = (short)f2bf(fmaxf(uu.w + vv.w + bb.w, 0.f));
      *(short4v*)&A[m * LDSW + hc] = s;
    }
  }
  __syncthreads();

  const int nbase = wave * 32;       // 16 waves x 32 cols = 512
  f32x4 acc[9][2];

  // layer cb
  zero_acc<9, 2>(acc);
  gemm_kloop<9, 2>(A, Wcb, lane, nbase, acc);
  __syncthreads();                 // all waves done reading E0
  store_relu_lds<9, 2>(A, bcb, lane, nbase, acc);
  __syncthreads();

  // layer cc
  zero_acc<9, 2>(acc);
  gemm_kloop<9, 2>(A, Wcc, lane, nbase, acc);
  __syncthreads();
  store_relu_lds<9, 2>(A, bcc, lane, nbase, acc);
  __syncthreads();

  // final: out = E2 @ Wout^T + bout.  k-split across waves 0-7 (64 k each),
  // n padded 2->16.
  if (wave < 8) {
    f32x4 oacc[9];
#pragma unroll
    for (int mt = 0; mt < 9; ++mt) { f32x4 z = {0.f, 0.f, 0.f, 0.f}; oacc[mt] = z; }
    const int n = lane & 15, kg2 = lane >> 4;
#pragma unroll
    for (int kk = 0; kk < 2; ++kk) {
      const int k0 = wave * 64 + kk * 32 + kg2 * 8;
      short8 bf = {0, 0, 0, 0, 0, 0, 0, 0};
      if (n < 2) bf = *(const short8*)(Wout + n * 512 + k0);
#pragma unroll
      for (int mt = 0; mt < 9; ++mt) {
        const short8 af = *(const short8*)(A + (mt * 16 + n) * LDSW + k0);
        oacc[mt] = __builtin_amdgcn_mfma_f32_16x16x32_bf16(af, bf, oacc[mt], 0, 0, 0);
      }
    }
    if (n < 2) {
#pragma unroll
      for (int mt = 0; mt < 9; ++mt)
#pragma unroll
        for (int r = 0; r < 4; ++r) {
          const int row = mt * 16 + kg2 * 4 + r;
          red[(row * 2 + n) * 8 + wave] = oacc[mt][r];
        }
    }
  }
  __syncthreads();
  if (tid < 288) {
    const int row = tid >> 1, o = tid & 1;
    float s = bout[o];
#pragma unroll
    for (int w = 0; w < 8; ++w) s += red[(row * 2 + o) * 8 + w];
    const int ii = (row >= 96) ? 2 : (row >= 48 ? 1 : 0);
    const int jj = row - ii * 48;
    out[((b * 192 + ip * 3 + ii) * 192 + jt * 48 + jj) * 2 + o] = s;
  }
}

extern "C" void kernel_launch(void* const* d_in, const int* in_sizes, int n_in,
                              void* d_out, int out_size, void* d_ws, size_t ws_size,
                              hipStream_t stream) {
  const float* bv   = (const float*)d_in[0];
  const float* xy   = (const float*)d_in[1];
  const float* Wxy  = (const float*)d_in[2];
  const float* bxy  = (const float*)d_in[3];
  const float* Wa   = (const float*)d_in[4];
  const float* ba   = (const float*)d_in[5];
  const float* Wb   = (const float*)d_in[6];
  const float* bb   = (const float*)d_in[7];
  const float* Wca  = (const float*)d_in[8];
  const float* bca  = (const float*)d_in[9];
  const float* Wcb  = (const float*)d_in[10];
  const float* bcb  = (const float*)d_in[11];
  const float* Wcc  = (const float*)d_in[12];
  const float* bcc  = (const float*)d_in[13];
  const float* Wout = (const float*)d_in[14];
  const float* bout = (const float*)d_in[15];
  float* out = (float*)d_out;

  // ws layout (bytes): [0, 3,147,776) bf16 weights (tiled layout);
  // f1 bf16 @3,147,776 (aliased by u fp32, f1 dead before L3 writes u);
  // f2 bf16 @4,720,640; v fp32 @5,507,072; end 7,079,936.
  short* S = (short*)d_ws;
  char* base = (char*)d_ws;
  short* WaB   = S;
  short* WbB   = S + 262144;
  short* WuvB  = S + 524288;    // tiled, 1024 cols: ct 0-31 = W1 (u), 32-63 = W2 (v)
  short* WcbB  = S + 1048576;
  short* WccB  = S + 1310720;
  short* WoutB = S + 1572864;
  short* f1 = (short*)(base + 3147776);
  float* u  = (float*)(base + 3147776);
  short* f2 = (short*)(base + 4720640);
  float* v  = (float*)(base + 5507072);

  prep_kernel<<<512, 256, 0, stream>>>(Wa, Wb, Wca, Wcb, Wcc, Wout, S);
  node_layer<1><<<384, 256, 0, stream>>>(bv, WaB, ba, xy, Wxy, bxy, f1, nullptr, 8);
  node_layer<2><<<384, 256, 0, stream>>>(f1, WbB, bb, nullptr, nullptr, nullptr, f2, nullptr, 8);
  node_layer<3><<<768, 256, 0, stream>>>(f2, WuvB, nullptr, nullptr, nullptr, nullptr, u, v, 16);
  edge_kernel<<<1024, 1024, 0, stream>>>(u, v, WcbB, WccB, WoutB, bca, bcb, bcc, bout, out);
}

// Round 10
// 307.095 us; speedup vs baseline: 1.0416x; 1.0416x over previous
//
#include <hip/hip_runtime.h>

// BrickVectorEdgeModel on MI355X (gfx950).
// R17: edge 16-wave TLP, third attempt. Empirical __launch_bounds__ rule on
// this toolchain (3 data points): 2nd arg ~ WORKGROUPS/CU; VGPR cap =
// 512/(arg*wavesPerBlock/4). (512,2)->128 ok; (512,4)->64 spill (R12);
// (1024,4)->64 spill (R16, WRITE 283MB). Fix: (1024,1) -> 16 waves/CU ->
// cap 128; acc[9][2]=72+operands ~115 fits. R16's spill also showed scratch
// ran at 2TB/s -> no bandwidth wall anywhere near; latency theory intact.
// R7's 2-waves/SIMD was register-forced (128 VGPR + 144 AGPR acc[9][4]);
// 16 waves x NT=2 halves acc -> 4 waves/SIMD genuinely reachable.
// Same 144-row tile / 1024 blocks / W-per-CU as R7 (the proven minimum).
// Nodes/prep: R14-exact. WRITE_SIZE is the spill canary.
// Tiled W layout (per 512-col weight, elems): off(c,k) =
//   ((c>>4)*16 + (k>>5))*512 + (c&15)*32 + (k&31)

typedef short  short8  __attribute__((ext_vector_type(8)));
typedef short  short4v __attribute__((ext_vector_type(4)));
typedef float  f32x4   __attribute__((ext_vector_type(4)));

#define LDSW 520   // LDS row stride in bf16 elems (520*2B = 1040B, 16B-aligned)

__device__ inline unsigned short f2bf(float x) {
  unsigned u = __float_as_uint(x);
  unsigned r = (u + 0x7FFFu + ((u >> 16) & 1u)) >> 16;  // RNE
  return (unsigned short)r;
}

__device__ __host__ inline int wtile_off(int c, int k) {
  return ((c >> 4) * 16 + (k >> 5)) * 512 + (c & 15) * 32 + (k & 31);
}

template <int MT, int NT>
__device__ inline void zero_acc(f32x4 (&acc)[MT][NT]) {
#pragma unroll
  for (int mt = 0; mt < MT; ++mt)
#pragma unroll
    for (int nt = 0; nt < NT; ++nt) {
      f32x4 z = {0.f, 0.f, 0.f, 0.f};
      acc[mt][nt] = z;
    }
}

// acc[mt][nt] (+)= W-tile x E-tile.  W as MFMA A-operand (m = out-col),
// E as B-operand (n = edge-row).  Lane holds 4 consecutive out-cols
// (kg*4+r) at edge-row (mt*16 + (lane&15)).
// W is in tiled layout: per (col_tile ct, ks) a contiguous 1KB fragment;
// lane's slice at (lane&15)*32 + (lane>>4)*8.  One wF load = coalesced 1KB.
// wF register double-buffered across ks; eF JIT from LDS, rotating 1-deep.
template <int MT, int NT>
__device__ inline void gemm_kloop(const short* E, const short* __restrict__ W,
                                  int lane, int nbase, f32x4 (&acc)[MT][NT]) {
  const int mrow = lane & 15, kg = lane >> 4;
  const short* El = E + mrow * LDSW + kg * 8;
  const short* Wl = W + (nbase >> 4) * 8192 + mrow * 32 + kg * 8;
  short8 wF[2][NT];
#pragma unroll
  for (int nt = 0; nt < NT; ++nt) wF[0][nt] = *(const short8*)(Wl + nt * 8192);
#pragma unroll
  for (int ks = 0; ks < 16; ++ks) {
    const int cur = ks & 1, nxt = cur ^ 1;
    if (ks < 15) {
      const int k1 = (ks + 1) * 512;
#pragma unroll
      for (int nt = 0; nt < NT; ++nt)
        wF[nxt][nt] = *(const short8*)(Wl + nt * 8192 + k1);
    }
    const int k0 = ks * 32;
    short8 e0 = *(const short8*)(El + k0);
#pragma unroll
    for (int mt = 0; mt < MT; ++mt) {
      const short8 ecur = e0;
      if (mt < MT - 1) e0 = *(const short8*)(El + (mt + 1) * 16 * LDSW + k0);
#pragma unroll
      for (int nt = 0; nt < NT; ++nt)
        acc[mt][nt] = __builtin_amdgcn_mfma_f32_16x16x32_bf16(
            wF[cur][nt], ecur, acc[mt][nt], 0, 0, 0);
    }
  }
}

// relu(acc + bias[outcol]) -> bf16 -> LDS, 8B vector writes.
template <int MT, int NT>
__device__ inline void store_relu_lds(short* E, const float* __restrict__ bias,
                                      int lane, int nbase, f32x4 (&acc)[MT][NT]) {
  const int mrow = lane & 15, kg = lane >> 4;
#pragma unroll
  for (int nt = 0; nt < NT; ++nt) {
    const int oc = nbase + nt * 16 + kg * 4;
    const float4 bs = *(const float4*)(bias + oc);
#pragma unroll
    for (int mt = 0; mt < MT; ++mt) {
      short4v s;
      s.x = (short)f2bf(fmaxf(acc[mt][nt][0] + bs.x, 0.f));
      s.y = (short)f2bf(fmaxf(acc[mt][nt][1] + bs.y, 0.f));
      s.z = (short)f2bf(fmaxf(acc[mt][nt][2] + bs.z, 0.f));
      s.w = (short)f2bf(fmaxf(acc[mt][nt][3] + bs.w, 0.f));
      *(short4v*)&E[(mt * 16 + mrow) * LDSW + oc] = s;
    }
  }
}

// ---------------- prep: fp32 -> bf16 + tiled relayout ----------------
__global__ void prep_kernel(const float* __restrict__ Wa, const float* __restrict__ Wb,
                            const float* __restrict__ Wca, const float* __restrict__ Wcb,
                            const float* __restrict__ Wcc, const float* __restrict__ Wout,
                            short* __restrict__ outS) {
  const int tid = blockIdx.x * blockDim.x + threadIdx.x;
  const int stride = gridDim.x * blockDim.x;
  const int M = 262144;
  for (int i = tid; i < 6 * M + 1024; i += stride) {
    float x;
    int dst;
    if (i < M) {                       // WaB tiled
      const int c = i >> 9, k = i & 511;
      x = Wa[i];
      dst = wtile_off(c, k);
    } else if (i < 2 * M) {            // WbB tiled
      const int t = i - M, c = t >> 9, k = t & 511;
      x = Wb[t];
      dst = M + wtile_off(c, k);
    } else if (i < 3 * M) {            // Wuv: u-half, tiled cols 0..511
      const int t = i - 2 * M, c = t >> 9, k = t & 511;
      x = Wca[c * 1024 + k];
      dst = 2 * M + wtile_off(c, k);
    } else if (i < 4 * M) {            // Wuv: v-half, tiled cols 512..1023
      const int t = i - 3 * M, c = t >> 9, k = t & 511;
      x = Wca[c * 1024 + 512 + k];
      dst = 2 * M + wtile_off(512 + c, k);
    } else if (i < 5 * M) {            // WcbB tiled
      const int t = i - 4 * M, c = t >> 9, k = t & 511;
      x = Wcb[t];
      dst = 4 * M + wtile_off(c, k);
    } else if (i < 6 * M) {            // WccB tiled
      const int t = i - 5 * M, c = t >> 9, k = t & 511;
      x = Wcc[t];
      dst = 5 * M + wtile_off(c, k);
    } else {                           // Wout plain row-major
      x = Wout[i - 6 * M];
      dst = i;
    }
    outS[dst] = (short)f2bf(x);
  }
}

// ---------------- node stage: 3 per-layer tiled kernels (16 rows x 64 cols) --
// R14-proven: grids 384/384/768 fill all 256 CUs, ~6 resident blocks/CU.
template <int MODE>
__global__ __launch_bounds__(256, 4) void node_layer(
    const void* __restrict__ Xin, const short* __restrict__ W,
    const float* __restrict__ bias, const float* __restrict__ xy,
    const float* __restrict__ Wxy, const float* __restrict__ bxy,
    void* __restrict__ Yout, float* __restrict__ vout, int colTiles) {
  __shared__ short X[16 * LDSW];
  __shared__ float xyl[32];
  const int tid = threadIdx.x, lane = tid & 63, wave = tid >> 6;
  const int rt = blockIdx.x / colTiles, ct = blockIdx.x % colTiles;
  const int row0 = rt * 16, c0 = ct * 64;

  if (MODE == 1) {
    const float* bv = (const float*)Xin;
    const int hc = (tid & 127) * 4, m0 = tid >> 7;
    for (int m = m0; m < 16; m += 2) {
      const float4 t = *(const float4*)(bv + (row0 + m) * 512 + hc);
      short4v s;
      s.x = (short)f2bf(t.x); s.y = (short)f2bf(t.y);
      s.z = (short)f2bf(t.z); s.w = (short)f2bf(t.w);
      *(short4v*)&X[m * LDSW + hc] = s;
    }
    if (tid < 32) xyl[tid] = xy[row0 * 2 + tid];
  } else {
    const short* xb = (const short*)Xin;
    const int hc = (tid & 63) * 8, m0 = tid >> 6;
    for (int m = m0; m < 16; m += 4)
      *(short8*)&X[m * LDSW + hc] = *(const short8*)(xb + (row0 + m) * 512 + hc);
  }
  __syncthreads();

  const int nbase = c0 + wave * 16;
  f32x4 acc[1][1];
  zero_acc<1, 1>(acc);
  gemm_kloop<1, 1>(X, W, lane, nbase, acc);

  const int mrow = lane & 15, kg = lane >> 4;
  const int oc = nbase + kg * 4;
  if (MODE == 3) {
    float* u = (float*)Yout;
    const int row = row0 + mrow;
    if (oc < 512) *(f32x4*)&u[row * 512 + oc] = acc[0][0];     // block-uniform branch
    else          *(f32x4*)&vout[row * 512 + oc - 512] = acc[0][0];
  } else {
    short* Y = (short*)Yout;
    const float4 bs = *(const float4*)(bias + oc);
    float b2[4] = {0.f, 0.f, 0.f, 0.f}, w0[4], w1[4];
    if (MODE == 1) {
      const float4 t = *(const float4*)(bxy + oc);
      b2[0] = t.x; b2[1] = t.y; b2[2] = t.z; b2[3] = t.w;
#pragma unroll
      for (int r = 0; r < 4; ++r) { w0[r] = Wxy[(oc + r) * 2]; w1[r] = Wxy[(oc + r) * 2 + 1]; }
    }
    const int row = mrow;
    short4v s;
#pragma unroll
    for (int r = 0; r < 4; ++r) {
      float xv = acc[0][0][r] + ((const float*)&bs)[r];
      if (MODE == 1) xv += b2[r] + xyl[row * 2] * w0[r] + xyl[row * 2 + 1] * w1[r];
      ((short*)&s)[r] = (short)f2bf(fmaxf(xv, 0.f));
    }
    *(short4v*)&Y[(row0 + row) * 512 + oc] = s;
  }
}

// ---------------- edge stage: fused E0 -> E1 -> E2 -> out ----------------
// 144-row tiles (3 i x 48 j), 1024 blocks (4 full rounds), LDS 159KB ->
// 1 block/CU -- all R7-identical -- but 1024 THREADS (16 waves, 4/SIMD):
// each wave owns 32 out-cols (NT=2). Doubles latency-hiding TLP at
// IDENTICAL W-traffic. Final Wout phase: waves 0-7 only (red stays 9.2KB).
// __launch_bounds__(1024,1): empirical rule -> 16 waves/CU -> VGPR cap 128.
__global__ __launch_bounds__(1024, 1) void edge_kernel(
    const float* __restrict__ u, const float* __restrict__ v,
    const short* __restrict__ Wcb, const short* __restrict__ Wcc,
    const short* __restrict__ Wout,
    const float* __restrict__ bca, const float* __restrict__ bcb,
    const float* __restrict__ bcc, const float* __restrict__ bout,
    float* __restrict__ out) {
  __shared__ short A[144 * LDSW];      // 149,760 B
  __shared__ float red[144 * 2 * 8];   //   9,216 B
  const int tid = threadIdx.x, lane = tid & 63, wave = tid >> 6;
  const int blk = blockIdx.x;
  const int b = blk >> 8, rem = blk & 255, ip = rem >> 2, jt = rem & 3;
  const float* urow0 = u + (b * 192 + jt * 48) * 512;        // row m: j = jt*48 + m%48
  const float* vrow0 = v + (b * 192 + ip * 3) * 512;         // row m: i = ip*3 + m/48

  {  // Phase 0: E0 = relu(u[j] + v[i] + b_ca) -> bf16 LDS
    const int hc = (tid & 127) * 4, m0 = tid >> 7;   // m0 in 0..7
    const float4 v0 = *(const float4*)(vrow0 + hc);
    const float4 v1 = *(const float4*)(vrow0 + 512 + hc);
    const float4 v2 = *(const float4*)(vrow0 + 1024 + hc);
    const float4 bb = *(const float4*)(bca + hc);
#pragma unroll 2
    for (int m = m0; m < 144; m += 8) {
      const int ii = (m >= 96) ? 2 : (m >= 48 ? 1 : 0);
      const int jj = m - ii * 48;
      const float4 vv = (ii == 0) ? v0 : (ii == 1) ? v1 : v2;
      const float4 uu = *(const float4*)(urow0 + jj * 512 + hc);
      short4v s;
      s.x = (short)f2bf(fmaxf(uu.x + vv.x + bb.x, 0.f));
      s.y = (short)f2bf(fmaxf(uu.y + vv.y + bb.y, 0.f));
      s.z = (short)f2bf(fmaxf(uu.z + vv.z + bb.z, 0.f));
      s.w = (short)f2bf(fmaxf(uu.w + vv.w + bb.w, 0.f));
      *(short4v*)&A[m * LDSW + hc] = s;
    }
  }
  __syncthreads();

  const int nbase = wave * 32;       // 16 waves x 32 cols = 512
  f32x4 acc[9][2];

  // layer cb
  zero_acc<9, 2>(acc);
  gemm_kloop<9, 2>(A, Wcb, lane, nbase, acc);
  __syncthreads();                 // all waves done reading E0
  store_relu_lds<9, 2>(A, bcb, lane, nbase, acc);
  __syncthreads();

  // layer cc
  zero_acc<9, 2>(acc);
  gemm_kloop<9, 2>(A, Wcc, lane, nbase, acc);
  __syncthreads();
  store_relu_lds<9, 2>(A, bcc, lane, nbase, acc);
  __syncthreads();

  // final: out = E2 @ Wout^T + bout.  k-split across waves 0-7 (64 k each),
  // n padded 2->16.
  if (wave < 8) {
    f32x4 oacc[9];
#pragma unroll
    for (int mt = 0; mt < 9; ++mt) { f32x4 z = {0.f, 0.f, 0.f, 0.f}; oacc[mt] = z; }
    const int n = lane & 15, kg2 = lane >> 4;
#pragma unroll
    for (int kk = 0; kk < 2; ++kk) {
      const int k0 = wave * 64 + kk * 32 + kg2 * 8;
      short8 bf = {0, 0, 0, 0, 0, 0, 0, 0};
      if (n < 2) bf = *(const short8*)(Wout + n * 512 + k0);
#pragma unroll
      for (int mt = 0; mt < 9; ++mt) {
        const short8 af = *(const short8*)(A + (mt * 16 + n) * LDSW + k0);
        oacc[mt] = __builtin_amdgcn_mfma_f32_16x16x32_bf16(af, bf, oacc[mt], 0, 0, 0);
      }
    }
    if (n < 2) {
#pragma unroll
      for (int mt = 0; mt < 9; ++mt)
#pragma unroll
        for (int r = 0; r < 4; ++r) {
          const int row = mt * 16 + kg2 * 4 + r;
          red[(row * 2 + n) * 8 + wave] = oacc[mt][r];
        }
    }
  }
  __syncthreads();
  if (tid < 288) {
    const int row = tid >> 1, o = tid & 1;
    float s = bout[o];
#pragma unroll
    for (int w = 0; w < 8; ++w) s += red[(row * 2 + o) * 8 + w];
    const int ii = (row >= 96) ? 2 : (row >= 48 ? 1 : 0);
    const int jj = row - ii * 48;
    out[((b * 192 + ip * 3 + ii) * 192 + jt * 48 + jj) * 2 + o] = s;
  }
}

extern "C" void kernel_launch(void* const* d_in, const int* in_sizes, int n_in,
                              void* d_out, int out_size, void* d_ws, size_t ws_size,
                              hipStream_t stream) {
  const float* bv   = (const float*)d_in[0];
  const float* xy   = (const float*)d_in[1];
  const float* Wxy  = (const float*)d_in[2];
  const float* bxy  = (const float*)d_in[3];
  const float* Wa   = (const float*)d_in[4];
  const float* ba   = (const float*)d_in[5];
  const float* Wb   = (const float*)d_in[6];
  const float* bb   = (const float*)d_in[7];
  const float* Wca  = (const float*)d_in[8];
  const float* bca  = (const float*)d_in[9];
  const float* Wcb  = (const float*)d_in[10];
  const float* bcb  = (const float*)d_in[11];
  const float* Wcc  = (const float*)d_in[12];
  const float* bcc  = (const float*)d_in[13];
  const float* Wout = (const float*)d_in[14];
  const float* bout = (const float*)d_in[15];
  float* out = (float*)d_out;

  // ws layout (bytes): [0, 3,147,776) bf16 weights (tiled layout);
  // f1 bf16 @3,147,776 (aliased by u fp32, f1 dead before L3 writes u);
  // f2 bf16 @4,720,640; v fp32 @5,507,072; end 7,079,936.
  short* S = (short*)d_ws;
  char* base = (char*)d_ws;
  short* WaB   = S;
  short* WbB   = S + 262144;
  short* WuvB  = S + 524288;    // tiled, 1024 cols: ct 0-31 = W1 (u), 32-63 = W2 (v)
  short* WcbB  = S + 1048576;
  short* WccB  = S + 1310720;
  short* WoutB = S + 1572864;
  short* f1 = (short*)(base + 3147776);
  float* u  = (float*)(base + 3147776);
  short* f2 = (short*)(base + 4720640);
  float* v  = (float*)(base + 5507072);

  prep_kernel<<<512, 256, 0, stream>>>(Wa, Wb, Wca, Wcb, Wcc, Wout, S);
  node_layer<1><<<384, 256, 0, stream>>>(bv, WaB, ba, xy, Wxy, bxy, f1, nullptr, 8);
  node_layer<2><<<384, 256, 0, stream>>>(f1, WbB, bb, nullptr, nullptr, nullptr, f2, nullptr, 8);
  node_layer<3><<<768, 256, 0, stream>>>(f2, WuvB, nullptr, nullptr, nullptr, nullptr, u, v, 16);
  edge_kernel<<<1024, 1024, 0, stream>>>(u, v, WcbB, WccB, WoutB, bca, bcb, bcc, bout, out);
}

// Round 11
// 251.227 us; speedup vs baseline: 1.2733x; 1.2224x over previous
//
#include <hip/hip_runtime.h>

// BrickVectorEdgeModel on MI355X (gfx950).
// R18: E-prefetch depth 1->2 in gemm_kloop (the only untouched latency
// chain). Box closed by R12-R17: LDS caps tile at 144 rows -> 1 block/CU;
// RF caps 2 waves/SIMD (acc[9][4] in AGPR); 1024-thread blocks pin VGPR
// cap to 64 on this toolchain regardless of __launch_bounds__ (R16==R17
// byte-identical spills) -> 4 waves/SIMD unreachable. Edge = 990 TF = 40%
// of peak, at the known ~900TF 2-barrier-structure ceiling. Remaining
// computed exposure: E ds_read 1-deep = ~40-80cy exposed per mt x 9 x 16
// x 2 layers ~= 10-20us/block-path. Fix: 2-deep E rotation (issue mt+2's
// read during mt's MFMAs, ~80-160cy cover >= ~120cy LDS latency). +4 VGPR.
// If null: all knobs measured-null -> declare structural ceiling.
// Nodes/prep: R14-exact (best, 250.7us). WRITE_SIZE = spill canary.
// Tiled W layout (per 512-col weight, elems): off(c,k) =
//   ((c>>4)*16 + (k>>5))*512 + (c&15)*32 + (k&31)

typedef short  short8  __attribute__((ext_vector_type(8)));
typedef short  short4v __attribute__((ext_vector_type(4)));
typedef float  f32x4   __attribute__((ext_vector_type(4)));

#define LDSW 520   // LDS row stride in bf16 elems (520*2B = 1040B, 16B-aligned)

__device__ inline unsigned short f2bf(float x) {
  unsigned u = __float_as_uint(x);
  unsigned r = (u + 0x7FFFu + ((u >> 16) & 1u)) >> 16;  // RNE
  return (unsigned short)r;
}

__device__ __host__ inline int wtile_off(int c, int k) {
  return ((c >> 4) * 16 + (k >> 5)) * 512 + (c & 15) * 32 + (k & 31);
}

template <int MT, int NT>
__device__ inline void zero_acc(f32x4 (&acc)[MT][NT]) {
#pragma unroll
  for (int mt = 0; mt < MT; ++mt)
#pragma unroll
    for (int nt = 0; nt < NT; ++nt) {
      f32x4 z = {0.f, 0.f, 0.f, 0.f};
      acc[mt][nt] = z;
    }
}

// acc[mt][nt] (+)= W-tile x E-tile.  W as MFMA A-operand (m = out-col),
// E as B-operand (n = edge-row).  Lane holds 4 consecutive out-cols
// (kg*4+r) at edge-row (mt*16 + (lane&15)).
// W is in tiled layout: per (col_tile ct, ks) a contiguous 1KB fragment;
// lane's slice at (lane&15)*32 + (lane>>4)*8.  One wF load = coalesced 1KB.
// wF register double-buffered across ks; E rotates 2-deep across mt
// (R18: mt+2's ds_read issued under mt's MFMAs -> LDS latency covered).
template <int MT, int NT>
__device__ inline void gemm_kloop(const short* E, const short* __restrict__ W,
                                  int lane, int nbase, f32x4 (&acc)[MT][NT]) {
  const int mrow = lane & 15, kg = lane >> 4;
  const short* El = E + mrow * LDSW + kg * 8;
  const short* Wl = W + (nbase >> 4) * 8192 + mrow * 32 + kg * 8;
  short8 wF[2][NT];
#pragma unroll
  for (int nt = 0; nt < NT; ++nt) wF[0][nt] = *(const short8*)(Wl + nt * 8192);
#pragma unroll
  for (int ks = 0; ks < 16; ++ks) {
    const int cur = ks & 1, nxt = cur ^ 1;
    if (ks < 15) {
      const int k1 = (ks + 1) * 512;
#pragma unroll
      for (int nt = 0; nt < NT; ++nt)
        wF[nxt][nt] = *(const short8*)(Wl + nt * 8192 + k1);
    }
    const int k0 = ks * 32;
    short8 eA = *(const short8*)(El + k0);
    short8 eB = (MT > 1) ? *(const short8*)(El + 16 * LDSW + k0) : eA;
#pragma unroll
    for (int mt = 0; mt < MT; ++mt) {
      const short8 ecur = eA;
      eA = eB;
      if (mt + 2 < MT) eB = *(const short8*)(El + (mt + 2) * 16 * LDSW + k0);
#pragma unroll
      for (int nt = 0; nt < NT; ++nt)
        acc[mt][nt] = __builtin_amdgcn_mfma_f32_16x16x32_bf16(
            wF[cur][nt], ecur, acc[mt][nt], 0, 0, 0);
    }
  }
}

// relu(acc + bias[outcol]) -> bf16 -> LDS, 8B vector writes.
template <int MT, int NT>
__device__ inline void store_relu_lds(short* E, const float* __restrict__ bias,
                                      int lane, int nbase, f32x4 (&acc)[MT][NT]) {
  const int mrow = lane & 15, kg = lane >> 4;
#pragma unroll
  for (int nt = 0; nt < NT; ++nt) {
    const int oc = nbase + nt * 16 + kg * 4;
    const float4 bs = *(const float4*)(bias + oc);
#pragma unroll
    for (int mt = 0; mt < MT; ++mt) {
      short4v s;
      s.x = (short)f2bf(fmaxf(acc[mt][nt][0] + bs.x, 0.f));
      s.y = (short)f2bf(fmaxf(acc[mt][nt][1] + bs.y, 0.f));
      s.z = (short)f2bf(fmaxf(acc[mt][nt][2] + bs.z, 0.f));
      s.w = (short)f2bf(fmaxf(acc[mt][nt][3] + bs.w, 0.f));
      *(short4v*)&E[(mt * 16 + mrow) * LDSW + oc] = s;
    }
  }
}

// ---------------- prep: fp32 -> bf16 + tiled relayout ----------------
__global__ void prep_kernel(const float* __restrict__ Wa, const float* __restrict__ Wb,
                            const float* __restrict__ Wca, const float* __restrict__ Wcb,
                            const float* __restrict__ Wcc, const float* __restrict__ Wout,
                            short* __restrict__ outS) {
  const int tid = blockIdx.x * blockDim.x + threadIdx.x;
  const int stride = gridDim.x * blockDim.x;
  const int M = 262144;
  for (int i = tid; i < 6 * M + 1024; i += stride) {
    float x;
    int dst;
    if (i < M) {                       // WaB tiled
      const int c = i >> 9, k = i & 511;
      x = Wa[i];
      dst = wtile_off(c, k);
    } else if (i < 2 * M) {            // WbB tiled
      const int t = i - M, c = t >> 9, k = t & 511;
      x = Wb[t];
      dst = M + wtile_off(c, k);
    } else if (i < 3 * M) {            // Wuv: u-half, tiled cols 0..511
      const int t = i - 2 * M, c = t >> 9, k = t & 511;
      x = Wca[c * 1024 + k];
      dst = 2 * M + wtile_off(c, k);
    } else if (i < 4 * M) {            // Wuv: v-half, tiled cols 512..1023
      const int t = i - 3 * M, c = t >> 9, k = t & 511;
      x = Wca[c * 1024 + 512 + k];
      dst = 2 * M + wtile_off(512 + c, k);
    } else if (i < 5 * M) {            // WcbB tiled
      const int t = i - 4 * M, c = t >> 9, k = t & 511;
      x = Wcb[t];
      dst = 4 * M + wtile_off(c, k);
    } else if (i < 6 * M) {            // WccB tiled
      const int t = i - 5 * M, c = t >> 9, k = t & 511;
      x = Wcc[t];
      dst = 5 * M + wtile_off(c, k);
    } else {                           // Wout plain row-major
      x = Wout[i - 6 * M];
      dst = i;
    }
    outS[dst] = (short)f2bf(x);
  }
}

// ---------------- node stage: 3 per-layer tiled kernels (16 rows x 64 cols) --
// R14-proven: grids 384/384/768 fill all 256 CUs, ~6 resident blocks/CU.
template <int MODE>
__global__ __launch_bounds__(256, 4) void node_layer(
    const void* __restrict__ Xin, const short* __restrict__ W,
    const float* __restrict__ bias, const float* __restrict__ xy,
    const float* __restrict__ Wxy, const float* __restrict__ bxy,
    void* __restrict__ Yout, float* __restrict__ vout, int colTiles) {
  __shared__ short X[16 * LDSW];
  __shared__ float xyl[32];
  const int tid = threadIdx.x, lane = tid & 63, wave = tid >> 6;
  const int rt = blockIdx.x / colTiles, ct = blockIdx.x % colTiles;
  const int row0 = rt * 16, c0 = ct * 64;

  if (MODE == 1) {
    const float* bv = (const float*)Xin;
    const int hc = (tid & 127) * 4, m0 = tid >> 7;
    for (int m = m0; m < 16; m += 2) {
      const float4 t = *(const float4*)(bv + (row0 + m) * 512 + hc);
      short4v s;
      s.x = (short)f2bf(t.x); s.y = (short)f2bf(t.y);
      s.z = (short)f2bf(t.z); s.w = (short)f2bf(t.w);
      *(short4v*)&X[m * LDSW + hc] = s;
    }
    if (tid < 32) xyl[tid] = xy[row0 * 2 + tid];
  } else {
    const short* xb = (const short*)Xin;
    const int hc = (tid & 63) * 8, m0 = tid >> 6;
    for (int m = m0; m < 16; m += 4)
      *(short8*)&X[m * LDSW + hc] = *(const short8*)(xb + (row0 + m) * 512 + hc);
  }
  __syncthreads();

  const int nbase = c0 + wave * 16;
  f32x4 acc[1][1];
  zero_acc<1, 1>(acc);
  gemm_kloop<1, 1>(X, W, lane, nbase, acc);

  const int mrow = lane & 15, kg = lane >> 4;
  const int oc = nbase + kg * 4;
  if (MODE == 3) {
    float* u = (float*)Yout;
    const int row = row0 + mrow;
    if (oc < 512) *(f32x4*)&u[row * 512 + oc] = acc[0][0];     // block-uniform branch
    else          *(f32x4*)&vout[row * 512 + oc - 512] = acc[0][0];
  } else {
    short* Y = (short*)Yout;
    const float4 bs = *(const float4*)(bias + oc);
    float b2[4] = {0.f, 0.f, 0.f, 0.f}, w0[4], w1[4];
    if (MODE == 1) {
      const float4 t = *(const float4*)(bxy + oc);
      b2[0] = t.x; b2[1] = t.y; b2[2] = t.z; b2[3] = t.w;
#pragma unroll
      for (int r = 0; r < 4; ++r) { w0[r] = Wxy[(oc + r) * 2]; w1[r] = Wxy[(oc + r) * 2 + 1]; }
    }
    const int row = mrow;
    short4v s;
#pragma unroll
    for (int r = 0; r < 4; ++r) {
      float xv = acc[0][0][r] + ((const float*)&bs)[r];
      if (MODE == 1) xv += b2[r] + xyl[row * 2] * w0[r] + xyl[row * 2 + 1] * w1[r];
      ((short*)&s)[r] = (short)f2bf(fmaxf(xv, 0.f));
    }
    *(short4v*)&Y[(row0 + row) * 512 + oc] = s;
  }
}

// ---------------- edge stage: fused E0 -> E1 -> E2 -> out ----------------
// 144-row tiles (3 i x 48 j): LDS 158,976 B -> 1 block/CU, 8 waves.
// 1024 blocks = exactly 4 full rounds of 256 CUs. W/CU = 4.2 MB (minimum
// under the LDS cap). Only delta vs R7: 2-deep E rotation in gemm_kloop.
__global__ __launch_bounds__(512, 2) void edge_kernel(
    const float* __restrict__ u, const float* __restrict__ v,
    const short* __restrict__ Wcb, const short* __restrict__ Wcc,
    const short* __restrict__ Wout,
    const float* __restrict__ bca, const float* __restrict__ bcb,
    const float* __restrict__ bcc, const float* __restrict__ bout,
    float* __restrict__ out) {
  __shared__ short A[144 * LDSW];      // 149,760 B
  __shared__ float red[144 * 2 * 8];   //   9,216 B
  const int tid = threadIdx.x, lane = tid & 63, wave = tid >> 6;
  const int blk = blockIdx.x;
  const int b = blk >> 8, rem = blk & 255, ip = rem >> 2, jt = rem & 3;
  const float* urow0 = u + (b * 192 + jt * 48) * 512;        // row m: j = jt*48 + m%48
  const float* vrow0 = v + (b * 192 + ip * 3) * 512;         // row m: i = ip*3 + m/48

  {  // Phase 0: E0 = relu(u[j] + v[i] + b_ca) -> bf16 LDS
    const int hc = (tid & 127) * 4, m0 = tid >> 7;
    const float4 v0 = *(const float4*)(vrow0 + hc);
    const float4 v1 = *(const float4*)(vrow0 + 512 + hc);
    const float4 v2 = *(const float4*)(vrow0 + 1024 + hc);
    const float4 bb = *(const float4*)(bca + hc);
#pragma unroll 4
    for (int m = m0; m < 144; m += 4) {
      const int ii = (m >= 96) ? 2 : (m >= 48 ? 1 : 0);
      const int jj = m - ii * 48;
      const float4 vv = (ii == 0) ? v0 : (ii == 1) ? v1 : v2;
      const float4 uu = *(const float4*)(urow0 + jj * 512 + hc);
      short4v s;
      s.x = (short)f2bf(fmaxf(uu.x + vv.x + bb.x, 0.f));
      s.y = (short)f2bf(fmaxf(uu.y + vv.y + bb.y, 0.f));
      s.z = (short)f2bf(fmaxf(uu.z + vv.z + bb.z, 0.f));
      s.w = (short)f2bf(fmaxf(uu.w + vv.w + bb.w, 0.f));
      *(short4v*)&A[m * LDSW + hc] = s;
    }
  }
  __syncthreads();

  const int nbase = wave * 64;
  f32x4 acc[9][4];

  // layer cb
  zero_acc<9, 4>(acc);
  gemm_kloop<9, 4>(A, Wcb, lane, nbase, acc);
  __syncthreads();                 // all waves done reading E0
  store_relu_lds<9, 4>(A, bcb, lane, nbase, acc);
  __syncthreads();

  // layer cc
  zero_acc<9, 4>(acc);
  gemm_kloop<9, 4>(A, Wcc, lane, nbase, acc);
  __syncthreads();
  store_relu_lds<9, 4>(A, bcc, lane, nbase, acc);
  __syncthreads();

  // final: out = E2 @ Wout^T + bout.  k-split across 8 waves, n padded 2->16.
  f32x4 oacc[9];
#pragma unroll
  for (int mt = 0; mt < 9; ++mt) { f32x4 z = {0.f, 0.f, 0.f, 0.f}; oacc[mt] = z; }
  const int n = lane & 15, kg2 = lane >> 4;
#pragma unroll
  for (int kk = 0; kk < 2; ++kk) {
    const int k0 = wave * 64 + kk * 32 + kg2 * 8;
    short8 bf = {0, 0, 0, 0, 0, 0, 0, 0};
    if (n < 2) bf = *(const short8*)(Wout + n * 512 + k0);
#pragma unroll
    for (int mt = 0; mt < 9; ++mt) {
      const short8 af = *(const short8*)(A + (mt * 16 + n) * LDSW + k0);
      oacc[mt] = __builtin_amdgcn_mfma_f32_16x16x32_bf16(af, bf, oacc[mt], 0, 0, 0);
    }
  }
  if (n < 2) {
#pragma unroll
    for (int mt = 0; mt < 9; ++mt)
#pragma unroll
      for (int r = 0; r < 4; ++r) {
        const int row = mt * 16 + kg2 * 4 + r;
        red[(row * 2 + n) * 8 + wave] = oacc[mt][r];
      }
  }
  __syncthreads();
  if (tid < 288) {
    const int row = tid >> 1, o = tid & 1;
    float s = bout[o];
#pragma unroll
    for (int w = 0; w < 8; ++w) s += red[(row * 2 + o) * 8 + w];
    const int ii = (row >= 96) ? 2 : (row >= 48 ? 1 : 0);
    const int jj = row - ii * 48;
    out[((b * 192 + ip * 3 + ii) * 192 + jt * 48 + jj) * 2 + o] = s;
  }
}

extern "C" void kernel_launch(void* const* d_in, const int* in_sizes, int n_in,
                              void* d_out, int out_size, void* d_ws, size_t ws_size,
                              hipStream_t stream) {
  const float* bv   = (const float*)d_in[0];
  const float* xy   = (const float*)d_in[1];
  const float* Wxy  = (const float*)d_in[2];
  const float* bxy  = (const float*)d_in[3];
  const float* Wa   = (const float*)d_in[4];
  const float* ba   = (const float*)d_in[5];
  const float* Wb   = (const float*)d_in[6];
  const float* bb   = (const float*)d_in[7];
  const float* Wca  = (const float*)d_in[8];
  const float* bca  = (const float*)d_in[9];
  const float* Wcb  = (const float*)d_in[10];
  const float* bcb  = (const float*)d_in[11];
  const float* Wcc  = (const float*)d_in[12];
  const float* bcc  = (const float*)d_in[13];
  const float* Wout = (const float*)d_in[14];
  const float* bout = (const float*)d_in[15];
  float* out = (float*)d_out;

  // ws layout (bytes): [0, 3,147,776) bf16 weights (tiled layout);
  // f1 bf16 @3,147,776 (aliased by u fp32, f1 dead before L3 writes u);
  // f2 bf16 @4,720,640; v fp32 @5,507,072; end 7,079,936.
  short* S = (short*)d_ws;
  char* base = (char*)d_ws;
  short* WaB   = S;
  short* WbB   = S + 262144;
  short* WuvB  = S + 524288;    // tiled, 1024 cols: ct 0-31 = W1 (u), 32-63 = W2 (v)
  short* WcbB  = S + 1048576;
  short* WccB  = S + 1310720;
  short* WoutB = S + 1572864;
  short* f1 = (short*)(base + 3147776);
  float* u  = (float*)(base + 3147776);
  short* f2 = (short*)(base + 4720640);
  float* v  = (float*)(base + 5507072);

  prep_kernel<<<512, 256, 0, stream>>>(Wa, Wb, Wca, Wcb, Wcc, Wout, S);
  node_layer<1><<<384, 256, 0, stream>>>(bv, WaB, ba, xy, Wxy, bxy, f1, nullptr, 8);
  node_layer<2><<<384, 256, 0, stream>>>(f1, WbB, bb, nullptr, nullptr, nullptr, f2, nullptr, 8);
  node_layer<3><<<768, 256, 0, stream>>>(f2, WuvB, nullptr, nullptr, nullptr, nullptr, u, v, 16);
  edge_kernel<<<1024, 512, 0, stream>>>(u, v, WcbB, WccB, WoutB, bca, bcb, bcc, bout, out);
}

// Round 12
// 247.012 us; speedup vs baseline: 1.2950x; 1.0171x over previous
//
#include <hip/hip_runtime.h>

// BrickVectorEdgeModel on MI355X (gfx950).
// R19: byte-exact revert to R14 (best: wall 250.7us, edge 157.3us).
// R18's 2-deep E rotation spilled (WRITE 3.7->47MB; RF exactly full at
// acc[9][4]-AGPR + 128 VGPR) -- the last reachable knob, register-blocked.
// Complete measured box for the edge kernel (157us, 990 TF = 40% peak):
//   VALU count (R10) null; W-prefetch depth (R11) null; tile-size
//   occupancy (R13) blocked by W-replication slope (~11us/MB-W-per-CU);
//   32x32 MFMA (R15) blocked by grid granularity, per-row neutral;
//   16-wave TLP (R16/R17) blocked -- toolchain pins VGPR cap 64 at
//   1024-thread blocks regardless of __launch_bounds__; E-prefetch (R18)
//   blocked by full RF; bank conflicts measured cheap; HBM 1%, L2 ~20%.
// Wall-edge gap ~93us proven insensitive to node/prep structure
// (R0/R10/R11/R13/R14 fused/unfused/no-prep/4x-grids all ~90-107us).
// Tiled W layout (per 512-col weight, elems): off(c,k) =
//   ((c>>4)*16 + (k>>5))*512 + (c&15)*32 + (k&31)

typedef short  short8  __attribute__((ext_vector_type(8)));
typedef short  short4v __attribute__((ext_vector_type(4)));
typedef float  f32x4   __attribute__((ext_vector_type(4)));

#define LDSW 520   // LDS row stride in bf16 elems (520*2B = 1040B, 16B-aligned)

__device__ inline unsigned short f2bf(float x) {
  unsigned u = __float_as_uint(x);
  unsigned r = (u + 0x7FFFu + ((u >> 16) & 1u)) >> 16;  // RNE
  return (unsigned short)r;
}

__device__ __host__ inline int wtile_off(int c, int k) {
  return ((c >> 4) * 16 + (k >> 5)) * 512 + (c & 15) * 32 + (k & 31);
}

template <int MT, int NT>
__device__ inline void zero_acc(f32x4 (&acc)[MT][NT]) {
#pragma unroll
  for (int mt = 0; mt < MT; ++mt)
#pragma unroll
    for (int nt = 0; nt < NT; ++nt) {
      f32x4 z = {0.f, 0.f, 0.f, 0.f};
      acc[mt][nt] = z;
    }
}

// acc[mt][nt] (+)= W-tile x E-tile.  W as MFMA A-operand (m = out-col),
// E as B-operand (n = edge-row).  Lane holds 4 consecutive out-cols
// (kg*4+r) at edge-row (mt*16 + (lane&15)).
// W is in tiled layout: per (col_tile ct, ks) a contiguous 1KB fragment;
// lane's slice at (lane&15)*32 + (lane>>4)*8.  One wF load = coalesced 1KB.
// wF register double-buffered across ks; eF JIT from LDS, rotating 1-deep.
template <int MT, int NT>
__device__ inline void gemm_kloop(const short* E, const short* __restrict__ W,
                                  int lane, int nbase, f32x4 (&acc)[MT][NT]) {
  const int mrow = lane & 15, kg = lane >> 4;
  const short* El = E + mrow * LDSW + kg * 8;
  const short* Wl = W + (nbase >> 4) * 8192 + mrow * 32 + kg * 8;
  short8 wF[2][NT];
#pragma unroll
  for (int nt = 0; nt < NT; ++nt) wF[0][nt] = *(const short8*)(Wl + nt * 8192);
#pragma unroll
  for (int ks = 0; ks < 16; ++ks) {
    const int cur = ks & 1, nxt = cur ^ 1;
    if (ks < 15) {
      const int k1 = (ks + 1) * 512;
#pragma unroll
      for (int nt = 0; nt < NT; ++nt)
        wF[nxt][nt] = *(const short8*)(Wl + nt * 8192 + k1);
    }
    const int k0 = ks * 32;
    short8 e0 = *(const short8*)(El + k0);
#pragma unroll
    for (int mt = 0; mt < MT; ++mt) {
      const short8 ecur = e0;
      if (mt < MT - 1) e0 = *(const short8*)(El + (mt + 1) * 16 * LDSW + k0);
#pragma unroll
      for (int nt = 0; nt < NT; ++nt)
        acc[mt][nt] = __builtin_amdgcn_mfma_f32_16x16x32_bf16(
            wF[cur][nt], ecur, acc[mt][nt], 0, 0, 0);
    }
  }
}

// relu(acc + bias[outcol]) -> bf16 -> LDS, 8B vector writes.
template <int MT, int NT>
__device__ inline void store_relu_lds(short* E, const float* __restrict__ bias,
                                      int lane, int nbase, f32x4 (&acc)[MT][NT]) {
  const int mrow = lane & 15, kg = lane >> 4;
#pragma unroll
  for (int nt = 0; nt < NT; ++nt) {
    const int oc = nbase + nt * 16 + kg * 4;
    const float4 bs = *(const float4*)(bias + oc);
#pragma unroll
    for (int mt = 0; mt < MT; ++mt) {
      short4v s;
      s.x = (short)f2bf(fmaxf(acc[mt][nt][0] + bs.x, 0.f));
      s.y = (short)f2bf(fmaxf(acc[mt][nt][1] + bs.y, 0.f));
      s.z = (short)f2bf(fmaxf(acc[mt][nt][2] + bs.z, 0.f));
      s.w = (short)f2bf(fmaxf(acc[mt][nt][3] + bs.w, 0.f));
      *(short4v*)&E[(mt * 16 + mrow) * LDSW + oc] = s;
    }
  }
}

// ---------------- prep: fp32 -> bf16 + tiled relayout ----------------
__global__ void prep_kernel(const float* __restrict__ Wa, const float* __restrict__ Wb,
                            const float* __restrict__ Wca, const float* __restrict__ Wcb,
                            const float* __restrict__ Wcc, const float* __restrict__ Wout,
                            short* __restrict__ outS) {
  const int tid = blockIdx.x * blockDim.x + threadIdx.x;
  const int stride = gridDim.x * blockDim.x;
  const int M = 262144;
  for (int i = tid; i < 6 * M + 1024; i += stride) {
    float x;
    int dst;
    if (i < M) {                       // WaB tiled
      const int c = i >> 9, k = i & 511;
      x = Wa[i];
      dst = wtile_off(c, k);
    } else if (i < 2 * M) {            // WbB tiled
      const int t = i - M, c = t >> 9, k = t & 511;
      x = Wb[t];
      dst = M + wtile_off(c, k);
    } else if (i < 3 * M) {            // Wuv: u-half, tiled cols 0..511
      const int t = i - 2 * M, c = t >> 9, k = t & 511;
      x = Wca[c * 1024 + k];
      dst = 2 * M + wtile_off(c, k);
    } else if (i < 4 * M) {            // Wuv: v-half, tiled cols 512..1023
      const int t = i - 3 * M, c = t >> 9, k = t & 511;
      x = Wca[c * 1024 + 512 + k];
      dst = 2 * M + wtile_off(512 + c, k);
    } else if (i < 5 * M) {            // WcbB tiled
      const int t = i - 4 * M, c = t >> 9, k = t & 511;
      x = Wcb[t];
      dst = 4 * M + wtile_off(c, k);
    } else if (i < 6 * M) {            // WccB tiled
      const int t = i - 5 * M, c = t >> 9, k = t & 511;
      x = Wcc[t];
      dst = 5 * M + wtile_off(c, k);
    } else {                           // Wout plain row-major
      x = Wout[i - 6 * M];
      dst = i;
    }
    outS[dst] = (short)f2bf(x);
  }
}

// ---------------- node stage: 3 per-layer tiled kernels (16 rows x 64 cols) --
// MODE 1: X=bv fp32, out = relu(X@Wa^T + xy-term + ba + bxy) -> bf16
// MODE 2: X=f1 bf16, out = relu(X@Wb^T + bb) -> bf16
// MODE 3: X=f2 bf16, out = X@Wuv^T (1024 cols) -> fp32 u (cols<512) / v (>=512)
// 16-row tiles: LDS 16.6KB, ~6 resident blocks/CU; grids 384/384/768 fill
// all 256 CUs.
template <int MODE>
__global__ __launch_bounds__(256, 4) void node_layer(
    const void* __restrict__ Xin, const short* __restrict__ W,
    const float* __restrict__ bias, const float* __restrict__ xy,
    const float* __restrict__ Wxy, const float* __restrict__ bxy,
    void* __restrict__ Yout, float* __restrict__ vout, int colTiles) {
  __shared__ short X[16 * LDSW];
  __shared__ float xyl[32];
  const int tid = threadIdx.x, lane = tid & 63, wave = tid >> 6;
  const int rt = blockIdx.x / colTiles, ct = blockIdx.x % colTiles;
  const int row0 = rt * 16, c0 = ct * 64;

  if (MODE == 1) {
    const float* bv = (const float*)Xin;
    const int hc = (tid & 127) * 4, m0 = tid >> 7;
    for (int m = m0; m < 16; m += 2) {
      const float4 t = *(const float4*)(bv + (row0 + m) * 512 + hc);
      short4v s;
      s.x = (short)f2bf(t.x); s.y = (short)f2bf(t.y);
      s.z = (short)f2bf(t.z); s.w = (short)f2bf(t.w);
      *(short4v*)&X[m * LDSW + hc] = s;
    }
    if (tid < 32) xyl[tid] = xy[row0 * 2 + tid];
  } else {
    const short* xb = (const short*)Xin;
    const int hc = (tid & 63) * 8, m0 = tid >> 6;
    for (int m = m0; m < 16; m += 4)
      *(short8*)&X[m * LDSW + hc] = *(const short8*)(xb + (row0 + m) * 512 + hc);
  }
  __syncthreads();

  const int nbase = c0 + wave * 16;
  f32x4 acc[1][1];
  zero_acc<1, 1>(acc);
  gemm_kloop<1, 1>(X, W, lane, nbase, acc);

  const int mrow = lane & 15, kg = lane >> 4;
  const int oc = nbase + kg * 4;
  if (MODE == 3) {
    float* u = (float*)Yout;
    const int row = row0 + mrow;
    if (oc < 512) *(f32x4*)&u[row * 512 + oc] = acc[0][0];     // block-uniform branch
    else          *(f32x4*)&vout[row * 512 + oc - 512] = acc[0][0];
  } else {
    short* Y = (short*)Yout;
    const float4 bs = *(const float4*)(bias + oc);
    float b2[4] = {0.f, 0.f, 0.f, 0.f}, w0[4], w1[4];
    if (MODE == 1) {
      const float4 t = *(const float4*)(bxy + oc);
      b2[0] = t.x; b2[1] = t.y; b2[2] = t.z; b2[3] = t.w;
#pragma unroll
      for (int r = 0; r < 4; ++r) { w0[r] = Wxy[(oc + r) * 2]; w1[r] = Wxy[(oc + r) * 2 + 1]; }
    }
    const int row = mrow;
    short4v s;
#pragma unroll
    for (int r = 0; r < 4; ++r) {
      float xv = acc[0][0][r] + ((const float*)&bs)[r];
      if (MODE == 1) xv += b2[r] + xyl[row * 2] * w0[r] + xyl[row * 2 + 1] * w1[r];
      ((short*)&s)[r] = (short)f2bf(fmaxf(xv, 0.f));
    }
    *(short4v*)&Y[(row0 + row) * 512 + oc] = s;
  }
}

// ---------------- edge stage: fused E0 -> E1 -> E2 -> out ----------------
// 144-row tiles (3 i x 48 j): LDS 158,976 B -> 1 block/CU, 8 waves.
// 1024 blocks = exactly 4 full rounds of 256 CUs. W/CU = 4.2 MB (the
// minimum under the LDS cap; model: edge = ~115us fixed + ~11us/MB-W/CU).
__global__ __launch_bounds__(512, 2) void edge_kernel(
    const float* __restrict__ u, const float* __restrict__ v,
    const short* __restrict__ Wcb, const short* __restrict__ Wcc,
    const short* __restrict__ Wout,
    const float* __restrict__ bca, const float* __restrict__ bcb,
    const float* __restrict__ bcc, const float* __restrict__ bout,
    float* __restrict__ out) {
  __shared__ short A[144 * LDSW];      // 149,760 B
  __shared__ float red[144 * 2 * 8];   //   9,216 B
  const int tid = threadIdx.x, lane = tid & 63, wave = tid >> 6;
  const int blk = blockIdx.x;
  const int b = blk >> 8, rem = blk & 255, ip = rem >> 2, jt = rem & 3;
  const float* urow0 = u + (b * 192 + jt * 48) * 512;        // row m: j = jt*48 + m%48
  const float* vrow0 = v + (b * 192 + ip * 3) * 512;         // row m: i = ip*3 + m/48

  {  // Phase 0: E0 = relu(u[j] + v[i] + b_ca) -> bf16 LDS
    const int hc = (tid & 127) * 4, m0 = tid >> 7;
    const float4 v0 = *(const float4*)(vrow0 + hc);
    const float4 v1 = *(const float4*)(vrow0 + 512 + hc);
    const float4 v2 = *(const float4*)(vrow0 + 1024 + hc);
    const float4 bb = *(const float4*)(bca + hc);
#pragma unroll 4
    for (int m = m0; m < 144; m += 4) {
      const int ii = (m >= 96) ? 2 : (m >= 48 ? 1 : 0);
      const int jj = m - ii * 48;
      const float4 vv = (ii == 0) ? v0 : (ii == 1) ? v1 : v2;
      const float4 uu = *(const float4*)(urow0 + jj * 512 + hc);
      short4v s;
      s.x = (short)f2bf(fmaxf(uu.x + vv.x + bb.x, 0.f));
      s.y = (short)f2bf(fmaxf(uu.y + vv.y + bb.y, 0.f));
      s.z = (short)f2bf(fmaxf(uu.z + vv.z + bb.z, 0.f));
      s.w = (short)f2bf(fmaxf(uu.w + vv.w + bb.w, 0.f));
      *(short4v*)&A[m * LDSW + hc] = s;
    }
  }
  __syncthreads();

  const int nbase = wave * 64;
  f32x4 acc[9][4];

  // layer cb
  zero_acc<9, 4>(acc);
  gemm_kloop<9, 4>(A, Wcb, lane, nbase, acc);
  __syncthreads();                 // all waves done reading E0
  store_relu_lds<9, 4>(A, bcb, lane, nbase, acc);
  __syncthreads();

  // layer cc
  zero_acc<9, 4>(acc);
  gemm_kloop<9, 4>(A, Wcc, lane, nbase, acc);
  __syncthreads();
  store_relu_lds<9, 4>(A, bcc, lane, nbase, acc);
  __syncthreads();

  // final: out = E2 @ Wout^T + bout.  k-split across 8 waves, n padded 2->16.
  f32x4 oacc[9];
#pragma unroll
  for (int mt = 0; mt < 9; ++mt) { f32x4 z = {0.f, 0.f, 0.f, 0.f}; oacc[mt] = z; }
  const int n = lane & 15, kg2 = lane >> 4;
#pragma unroll
  for (int kk = 0; kk < 2; ++kk) {
    const int k0 = wave * 64 + kk * 32 + kg2 * 8;
    short8 bf = {0, 0, 0, 0, 0, 0, 0, 0};
    if (n < 2) bf = *(const short8*)(Wout + n * 512 + k0);
#pragma unroll
    for (int mt = 0; mt < 9; ++mt) {
      const short8 af = *(const short8*)(A + (mt * 16 + n) * LDSW + k0);
      oacc[mt] = __builtin_amdgcn_mfma_f32_16x16x32_bf16(af, bf, oacc[mt], 0, 0, 0);
    }
  }
  if (n < 2) {
#pragma unroll
    for (int mt = 0; mt < 9; ++mt)
#pragma unroll
      for (int r = 0; r < 4; ++r) {
        const int row = mt * 16 + kg2 * 4 + r;
        red[(row * 2 + n) * 8 + wave] = oacc[mt][r];
      }
  }
  __syncthreads();
  if (tid < 288) {
    const int row = tid >> 1, o = tid & 1;
    float s = bout[o];
#pragma unroll
    for (int w = 0; w < 8; ++w) s += red[(row * 2 + o) * 8 + w];
    const int ii = (row >= 96) ? 2 : (row >= 48 ? 1 : 0);
    const int jj = row - ii * 48;
    out[((b * 192 + ip * 3 + ii) * 192 + jt * 48 + jj) * 2 + o] = s;
  }
}

extern "C" void kernel_launch(void* const* d_in, const int* in_sizes, int n_in,
                              void* d_out, int out_size, void* d_ws, size_t ws_size,
                              hipStream_t stream) {
  const float* bv   = (const float*)d_in[0];
  const float* xy   = (const float*)d_in[1];
  const float* Wxy  = (const float*)d_in[2];
  const float* bxy  = (const float*)d_in[3];
  const float* Wa   = (const float*)d_in[4];
  const float* ba   = (const float*)d_in[5];
  const float* Wb   = (const float*)d_in[6];
  const float* bb   = (const float*)d_in[7];
  const float* Wca  = (const float*)d_in[8];
  const float* bca  = (const float*)d_in[9];
  const float* Wcb  = (const float*)d_in[10];
  const float* bcb  = (const float*)d_in[11];
  const float* Wcc  = (const float*)d_in[12];
  const float* bcc  = (const float*)d_in[13];
  const float* Wout = (const float*)d_in[14];
  const float* bout = (const float*)d_in[15];
  float* out = (float*)d_out;

  // ws layout (bytes): [0, 3,147,776) bf16 weights (tiled layout);
  // f1 bf16 @3,147,776 (aliased by u fp32, f1 dead before L3 writes u);
  // f2 bf16 @4,720,640; v fp32 @5,507,072; end 7,079,936.
  short* S = (short*)d_ws;
  char* base = (char*)d_ws;
  short* WaB   = S;
  short* WbB   = S + 262144;
  short* WuvB  = S + 524288;    // tiled, 1024 cols: ct 0-31 = W1 (u), 32-63 = W2 (v)
  short* WcbB  = S + 1048576;
  short* WccB  = S + 1310720;
  short* WoutB = S + 1572864;
  short* f1 = (short*)(base + 3147776);
  float* u  = (float*)(base + 3147776);
  short* f2 = (short*)(base + 4720640);
  float* v  = (float*)(base + 5507072);

  prep_kernel<<<512, 256, 0, stream>>>(Wa, Wb, Wca, Wcb, Wcc, Wout, S);
  node_layer<1><<<384, 256, 0, stream>>>(bv, WaB, ba, xy, Wxy, bxy, f1, nullptr, 8);
  node_layer<2><<<384, 256, 0, stream>>>(f1, WbB, bb, nullptr, nullptr, nullptr, f2, nullptr, 8);
  node_layer<3><<<768, 256, 0, stream>>>(f2, WuvB, nullptr, nullptr, nullptr, nullptr, u, v, 16);
  edge_kernel<<<1024, 512, 0, stream>>>(u, v, WcbB, WccB, WoutB, bca, bcb, bcc, bout, out);
}